// Round 3
// baseline (403.642 us; speedup 1.0000x reference)
//
#include <hip/hip_runtime.h>
#include <stdint.h>

// Problem: B=16, S=2048, I=1024, H=1024 (all fp32 in/out)
// out[b,s,h] = tanh( x[b,s,:]·W_ih[h,:] + b_ih[h] + hx[b,:]·W_hh[h,:] + b_hh[h] )
// GEMM: M = B*S = 32768, N = H = 1024, K = I = 1024.
// Round-3: A (X) staged as RAW fp32 via global_load_lds DMA (no VGPR
// round-trip), converted to bf16 at LDS->register fragment read. B (W_ih)
// pre-converted to bf16 by a tiny prep kernel that also computes h_term.

#define M_TOT 32768
#define N_TOT 1024
#define K_TOT 1024

typedef short short8 __attribute__((ext_vector_type(8)));   // 8 bf16 (4 VGPRs)
typedef float f32x4  __attribute__((ext_vector_type(4)));

// ---- workspace layout (bytes) ----
// [0, 2097152)        W_bf   : 1048576 bf16
// [2097152, 2162688)  h_term : 16384 fp32
#define WS_WBF_OFF 0
#define WS_HT_OFF  2097152

__device__ __forceinline__ unsigned int pack2_bf16_rne(float lo, float hi) {
    unsigned int a = __float_as_uint(lo);
    unsigned int b = __float_as_uint(hi);
    a = (a + 0x7fffu + ((a >> 16) & 1u)) >> 16;          // bf16(lo) low16
    b = (b + 0x7fffu + ((b >> 16) & 1u)) & 0xffff0000u;  // bf16(hi) high16
    return a | b;
}

__device__ __forceinline__ float fast_tanh(float z) {
    float e = __expf(2.0f * z);
    return 1.0f - 2.0f / (e + 1.0f);
}

// ---------------- prep: h_term (blocks 0..1023, one h each) + W convert (1024..1535) ----
__global__ void prep_kernel(const float* __restrict__ hx,
                            const float* __restrict__ whh,
                            const float* __restrict__ bih,
                            const float* __restrict__ bhh,
                            const float* __restrict__ wih,
                            unsigned short* __restrict__ wbf,
                            float* __restrict__ ht) {
    int bid = blockIdx.x;
    if (bid < 1024) {
        // h_term[b, h=bid] for all 16 b. Thread t owns K-slice [4t, 4t+4).
        __shared__ float red[16][256];
        const int h = bid;
        const int t = threadIdx.x;
        float4 wv = *(const float4*)(whh + (long long)h * 1024 + t * 4);
        float p[16];
#pragma unroll
        for (int b = 0; b < 16; ++b) {
            float4 xv = *(const float4*)(hx + (long long)b * 1024 + t * 4);
            p[b] = wv.x * xv.x + wv.y * xv.y + wv.z * xv.z + wv.w * xv.w;
        }
#pragma unroll
        for (int b = 0; b < 16; ++b) red[b][t] = p[b];
        __syncthreads();
        const int w = t >> 6, lane = t & 63;
#pragma unroll
        for (int bb = 0; bb < 4; ++bb) {
            int b = w * 4 + bb;
            float4 v = *(const float4*)(&red[b][lane * 4]);
            float s = v.x + v.y + v.z + v.w;
#pragma unroll
            for (int d = 32; d > 0; d >>= 1) s += __shfl_down(s, d, 64);
            if (lane == 0) ht[b * 1024 + h] = s + bih[h] + bhh[h];
        }
    } else {
        // W_ih fp32 -> bf16: 512 blocks x 256 threads x 8 elems = 1,048,576
        long long base = ((long long)(bid - 1024) * 256 + threadIdx.x) * 8;
        float4 a = *(const float4*)(wih + base);
        float4 b = *(const float4*)(wih + base + 4);
        uint4 o;
        o.x = pack2_bf16_rne(a.x, a.y);
        o.y = pack2_bf16_rne(a.z, a.w);
        o.z = pack2_bf16_rne(b.x, b.y);
        o.w = pack2_bf16_rne(b.z, b.w);
        *(uint4*)(wbf + base) = o;
    }
}

// ---------------- fused GEMM + tanh ----------------
// 128x128 tile, BK=32, 4 waves (2x2), each wave 64x64 via 4x4 MFMA 16x16x32.
// A tile: fp32 in LDS (16 KB), swizzled phys_slot = (logical + row) & 7 so
// both DMA writes and b128 fragment reads are evenly spread (8 words/bank).
// B tile: bf16 in LDS (8 KB), round-1 swizzle slot = (q + (row>>1)) & 3.
#define GLDS16(gp, lp) \
    __builtin_amdgcn_global_load_lds((const __attribute__((address_space(1))) void*)(gp), \
                                     (__attribute__((address_space(3))) void*)(lp), 16, 0, 0)

__global__ __launch_bounds__(256) void gemm_tanh_kernel(
    const float* __restrict__ X,            // [32768,1024] fp32
    const unsigned short* __restrict__ Bm,  // [1024,1024] bf16
    const float* __restrict__ ht,           // [16,1024]
    float* __restrict__ out)                // [32768,1024] fp32
{
    __shared__ __align__(16) char lds[24576];   // A fp32 [0,16384), B bf16 [16384,24576)

    const int tid = threadIdx.x;
    const int w = tid >> 6, l = tid & 63;

    // XCD swizzle: bid = x + 8*tile_n + 64*g ; tile_m = x*32+g. The 8 blocks
    // sharing an A row-tile are 8 apart -> same XCD if round-robin holds.
    const int bid = blockIdx.x;
    const int xcd = bid & 7;
    const int tile_n = (bid >> 3) & 7;
    const int g = bid >> 6;
    const int tile_m = xcd * 32 + g;
    const int m0 = tile_m << 7, n0 = tile_n << 7;

    // ---- A staging (fp32 DMA): 4 instr/wave; instr j covers rows w*32+j*8+(l>>3) ----
    const int arow = l >> 3;          // row within 8-row group
    const int aslot = l & 7;          // phys 16B slot
    const int aq = (aslot - arow) & 7;  // logical chunk (4 fp32) stored here
    const float* gA[4];
    char* ldsA[4];
#pragma unroll
    for (int j = 0; j < 4; ++j) {
        int rbase = w * 32 + j * 8;
        gA[j] = X + (long long)(m0 + rbase + arow) * K_TOT + aq * 4;
        ldsA[j] = lds + rbase * 128;          // lane writes base + l*16
    }

    // ---- B staging (bf16 DMA): 2 instr/wave ----
    const int r0 = (w * 2 + 0) * 16 + (l >> 2);
    const int r1 = (w * 2 + 1) * 16 + (l >> 2);
    const int bslot = l & 3;
    const int qg0 = (bslot - (r0 >> 1)) & 3;
    const int qg1 = (bslot - (r1 >> 1)) & 3;
    const unsigned short* gB0 = Bm + (long long)(n0 + r0) * K_TOT + qg0 * 8;
    const unsigned short* gB1 = Bm + (long long)(n0 + r1) * K_TOT + qg1 * 8;
    char* ldsB0 = lds + 16384 + (w * 2 + 0) * 1024;
    char* ldsB1 = lds + 16384 + (w * 2 + 1) * 1024;

    // ---- fragment read offsets ----
    const int wm = w & 1, wn = w >> 1;
    const int lm = l & 15, q = l >> 4;
    int offA0[4], offA1[4], offB[4];
#pragma unroll
    for (int t = 0; t < 4; ++t) {
        int rr = wm * 64 + t * 16 + lm;       // A row in tile
        int p0 = (2 * q + 0 + (rr & 7)) & 7;  // phys slot of logical 2q
        int p1 = (2 * q + 1 + (rr & 7)) & 7;
        offA0[t] = rr * 128 + p0 * 16;
        offA1[t] = rr * 128 + p1 * 16;
        int nn = wn * 64 + t * 16 + lm;       // B row (n) in tile
        offB[t] = 16384 + nn * 64 + (((q + (nn >> 1)) & 3) << 4);
    }

    f32x4 acc[4][4];
#pragma unroll
    for (int i = 0; i < 4; ++i)
#pragma unroll
        for (int j = 0; j < 4; ++j)
            acc[i][j] = (f32x4){0.f, 0.f, 0.f, 0.f};

    for (int k0 = 0; k0 < K_TOT; k0 += 32) {
#pragma unroll
        for (int j = 0; j < 4; ++j) GLDS16(gA[j] + k0, ldsA[j]);
        GLDS16(gB0 + k0, ldsB0);
        GLDS16(gB1 + k0, ldsB1);
        __syncthreads();   // drains vmcnt only (no lgkm chain on staging path)

        short8 af[4], bf[4];
#pragma unroll
        for (int t = 0; t < 4; ++t) {
            float4 f0 = *(const float4*)(lds + offA0[t]);   // k = 8q..8q+3
            float4 f1 = *(const float4*)(lds + offA1[t]);   // k = 8q+4..8q+7
            uint4 p;
            p.x = pack2_bf16_rne(f0.x, f0.y);
            p.y = pack2_bf16_rne(f0.z, f0.w);
            p.z = pack2_bf16_rne(f1.x, f1.y);
            p.w = pack2_bf16_rne(f1.z, f1.w);
            af[t] = *(short8*)&p;
            bf[t] = *(const short8*)(lds + offB[t]);
        }
#pragma unroll
        for (int mt = 0; mt < 4; ++mt)
#pragma unroll
            for (int nt = 0; nt < 4; ++nt)
                acc[mt][nt] = __builtin_amdgcn_mfma_f32_16x16x32_bf16(
                    af[mt], bf[nt], acc[mt][nt], 0, 0, 0);
        __syncthreads();
    }

    // ---- epilogue: out = tanh(acc + h_term[b, n]) ----
    // C/D layout: col = lane&15 (n), row = (lane>>4)*4 + reg (m)
    const int b = tile_m >> 4;
    float htv[4];
#pragma unroll
    for (int nt = 0; nt < 4; ++nt)
        htv[nt] = ht[b * 1024 + n0 + wn * 64 + nt * 16 + lm];

#pragma unroll
    for (int mt = 0; mt < 4; ++mt) {
#pragma unroll
        for (int nt = 0; nt < 4; ++nt) {
            int n = n0 + wn * 64 + nt * 16 + lm;
#pragma unroll
            for (int r = 0; r < 4; ++r) {
                int m = m0 + wm * 64 + mt * 16 + q * 4 + r;
                float z = acc[mt][nt][r] + htv[nt];
                out[(long long)m * N_TOT + n] = fast_tanh(z);
            }
        }
    }
}

extern "C" void kernel_launch(void* const* d_in, const int* in_sizes, int n_in,
                              void* d_out, int out_size, void* d_ws, size_t ws_size,
                              hipStream_t stream) {
    const float* x    = (const float*)d_in[0];
    const float* hx   = (const float*)d_in[1];
    const float* wih  = (const float*)d_in[2];
    const float* whh  = (const float*)d_in[3];
    const float* bih  = (const float*)d_in[4];
    const float* bhh  = (const float*)d_in[5];
    float* out = (float*)d_out;

    unsigned short* wbf = (unsigned short*)((char*)d_ws + WS_WBF_OFF);
    float*          htp = (float*)((char*)d_ws + WS_HT_OFF);

    // prep: h_term (1024 blocks) + W convert (512 blocks)
    prep_kernel<<<1536, 256, 0, stream>>>(hx, whh, bih, bhh, wih, wbf, htp);
    // fused GEMM + tanh: 256 m-tiles x 8 n-tiles, XCD-swizzled
    gemm_tanh_kernel<<<2048, 256, 0, stream>>>(x, wbf, htp, out);
}